// Round 8
// baseline (118.957 us; speedup 1.0000x reference)
//
#include <hip/hip_runtime.h>
#include <hip/hip_bf16.h>

// Interpolator == attention: out = softmax_c(z_t^T (W+W^T) z_c - q_cc[c]) @ y_context
// Msym = log2e*(W+W^T) f32; Q = z_target @ Msym (hi/lo bf16); K = z_context (hi/lo bf16)
// bias[c] = -0.5 * z_c^T Msym z_c (f32); V^T bf16 [32][8192].
// attn: NO online max (exp2-domain logits |s|<~60 fit f32/bf16 exponent range).
// 256 blocks x 512 thr; 8 waves = 4 context-slices x 2 target-halves sharing a
// 128-context K/V supertile staged in LDS via global_load_lds (pre-swizzled
// source, XOR-swizzled reads), double-buffered, 2-phase barrier pipeline.

typedef float f32x4 __attribute__((ext_vector_type(4)));
typedef __bf16 bf16x8 __attribute__((ext_vector_type(8)));

#define LOG2E 1.4426950408889634f

static __device__ __forceinline__ unsigned short f2bf(float x) {
  unsigned u = __float_as_uint(x);
  u += 0x7fffu + ((u >> 16) & 1u);   // RNE
  return (unsigned short)(u >> 16);
}
static __device__ __forceinline__ float bf2f(unsigned short h) {
  return __uint_as_float(((unsigned)h) << 16);
}
static __device__ __forceinline__ bf16x8 ldg8(const unsigned short* p) {
  uint4 u = *reinterpret_cast<const uint4*>(p);
  return __builtin_bit_cast(bf16x8, u);
}
static __device__ __forceinline__ unsigned cvt_pk_bf16(float lo, float hi) {
  unsigned r;
  asm("v_cvt_pk_bf16_f32 %0, %1, %2" : "=v"(r) : "v"(lo), "v"(hi));
  return r;
}
// direct global->LDS DMA, 16B/lane; LDS dest = wave-uniform base + lane*16
static __device__ __forceinline__ void gl2lds(const unsigned short* g, unsigned short* l) {
  __builtin_amdgcn_global_load_lds(
      (const __attribute__((address_space(1))) unsigned int*)g,
      (__attribute__((address_space(3))) unsigned int*)l, 16, 0, 0);
}

__global__ void msym_kernel(const float* __restrict__ W, float* __restrict__ Msym) {
  int idx = blockIdx.x * 256 + threadIdx.x;   // 16 blocks -> 4096 elems
  int k = idx >> 6, d = idx & 63;
  Msym[idx] = LOG2E * (W[k * 64 + d] + W[d * 64 + k]);
}

// grid 6176: [0,2048) Q | [2048,4096) K | [4096,6144) bias | [6144,6176) V-transpose
__global__ void prep_kernel(const float* __restrict__ zc, const float* __restrict__ yc,
                            const float* __restrict__ zt, const float* __restrict__ Msym,
                            unsigned short* __restrict__ Qh, unsigned short* __restrict__ Ql,
                            unsigned short* __restrict__ Kh, unsigned short* __restrict__ Kl,
                            unsigned short* __restrict__ Vt, float* __restrict__ bias)
{
  int b = blockIdx.x, tid = threadIdx.x;
  if (b < 2048) {                       // Q = z_t @ Msym, hi/lo split (coalesced Msym)
    int idx = b * 256 + tid;
    int t = idx >> 6, d = idx & 63;
    const float* z = zt + t * 64;
    float q = 0.f;
    #pragma unroll 8
    for (int k = 0; k < 64; ++k) q = fmaf(z[k], Msym[k * 64 + d], q);
    unsigned short h = f2bf(q);
    Qh[idx] = h;
    Ql[idx] = f2bf(q - bf2f(h));
  } else if (b < 4096) {                // K hi/lo split
    int idx = (b - 2048) * 256 + tid;
    float v = zc[idx];
    unsigned short h = f2bf(v);
    Kh[idx] = h;
    Kl[idx] = f2bf(v - bf2f(h));
  } else if (b < 6144) {                // bias[c] = -0.5 * z_c^T Msym z_c, one wave per c
    int c = (b - 4096) * 4 + (tid >> 6), j = tid & 63;
    const float* z = zc + c * 64;
    float cs = 0.f;
    #pragma unroll 8
    for (int i = 0; i < 64; ++i) cs = fmaf(z[i], Msym[i * 64 + j], cs);
    float part = cs * z[j];
    #pragma unroll
    for (int off = 32; off >= 1; off >>= 1) part += __shfl_xor(part, off, 64);
    if (j == 0) bias[c] = -0.5f * part;
  } else {                              // V transpose via LDS (alignment-safe)
    __shared__ float vt[256][33];
    int cbase = (b - 6144) * 256;       // 256 contexts per block
    #pragma unroll
    for (int k = 0; k < 32; ++k) {
      int e = k * 256 + tid;            // e = c_rel*32 + dy, coalesced read
      vt[e >> 5][e & 31] = yc[cbase * 32 + e];
    }
    __syncthreads();
    #pragma unroll
    for (int k = 0; k < 32; ++k)        // k = dy; consecutive tid -> consecutive c
      Vt[k * 8192 + cbase + tid] = f2bf(vt[tid][k]);
  }
}

// ---------------- attention kernel ----------------
// LDS supertile: 128 contexts. KhL/KlL rows = 128B (64 bf16), 8 chunks of 16B,
// physical chunk p holds logical chunk p ^ (row&7). VL rows = 256B (128 bf16),
// 16 chunks, physical p holds logical p ^ (row&15) (row = dy, &15 == lane row).
// Staging pre-swizzles the GLOBAL source so LDS dest stays linear (m173 pattern).

#define STAGE(NB, ST) { \
  const int C0_ = (ST) * 128; \
  _Pragma("unroll") \
  for (int i2 = 0; i2 < 2; ++i2) { \
    int i = wid + i2 * 8;                       /* Kh/Kl instr 0..15 */ \
    int row = i * 8 + (lane >> 3); \
    int lchunk = (lane & 7) ^ (row & 7); \
    gl2lds(Kh + (C0_ + row) * 64 + lchunk * 8, &KhL[NB][i * 512]); \
    gl2lds(Kl + (C0_ + row) * 64 + lchunk * 8, &KlL[NB][i * 512]); \
  } \
  { \
    int row = wid * 4 + (lane >> 4);            /* V instr = wid, rows = dy */ \
    int lchunk = (lane & 15) ^ (row & 15); \
    gl2lds(Vt + row * 8192 + C0_ + lchunk * 8, &VL[NB][wid * 512]); \
  } }

__global__ __launch_bounds__(512, 1) void attn_kernel(
    const unsigned short* __restrict__ Qh, const unsigned short* __restrict__ Ql,
    const unsigned short* __restrict__ Kh, const unsigned short* __restrict__ Kl,
    const unsigned short* __restrict__ Vt, const float* __restrict__ bias,
    float* __restrict__ out)
{
  __shared__ unsigned short KhL[2][128 * 64];   // 2 x 16 KB
  __shared__ unsigned short KlL[2][128 * 64];   // 2 x 16 KB
  __shared__ unsigned short VL[2][32 * 128];    // 2 x 8 KB
  __shared__ uint2 p_lds[8][16][10];            // wave-private P relayout (8 used + 2 pad)
  __shared__ float acc_lds[8][16][32];          // combine: [wave][t_rel][dy]
  __shared__ float den_lds[8][16];              // combine: [wave][t_rel]

  const int tid = threadIdx.x;
  const int wid = tid >> 6, lane = tid & 63;
  const int lr = lane & 15, g = lane >> 4;
  const int sl = wid & 3, hf = wid >> 2;        // context slice, target half
  const int tbase = blockIdx.x * 32;

  // Q fragments (B-operand): lane holds Q[tbase + hf*16 + lr][f*32 + 8g .. +7]
  bf16x8 qh[2], ql[2];
  #pragma unroll
  for (int f = 0; f < 2; ++f) {
    int off = (tbase + hf * 16 + lr) * 64 + f * 32 + 8 * g;
    qh[f] = ldg8(Qh + off);
    ql[f] = ldg8(Ql + off);
  }

  uint4 ones_bits = make_uint4(0x3F803F80u, 0x3F803F80u, 0x3F803F80u, 0x3F803F80u);
  bf16x8 vones = __builtin_bit_cast(bf16x8, ones_bits);

  f32x4 acc[2];                                 // [dyb]; D: t_rel=4g+r, dy=dyb*16+lr
  f32x4 den;                                    // denominator (all dy cols equal)
  acc[0] = (f32x4)(0.0f);
  acc[1] = (f32x4)(0.0f);
  den = (f32x4)(0.0f);

  STAGE(0, 0)
  __syncthreads();

  for (int st = 0; st < 64; ++st) {
    const int cur = st & 1;
    if (st + 1 < 64) STAGE(cur ^ 1, st + 1)

    // --- K fragments from LDS (A-operand): rows c = sl*32 + cb*16 + lr ---
    bf16x8 kh[2][2], kl[2][2];
    #pragma unroll
    for (int cb = 0; cb < 2; ++cb) {
      int row = sl * 32 + cb * 16 + lr;
      #pragma unroll
      for (int f = 0; f < 2; ++f) {
        int phys = (f * 4 + g) ^ (row & 7);
        int off = row * 64 + phys * 8;
        kh[cb][f] = __builtin_bit_cast(bf16x8, *reinterpret_cast<const uint4*>(&KhL[cur][off]));
        kl[cb][f] = __builtin_bit_cast(bf16x8, *reinterpret_cast<const uint4*>(&KlL[cur][off]));
      }
    }
    // --- V fragments (B-operand): V[c = C0+sl*32+8g..+7][dy = dyb*16+lr] ---
    bf16x8 vf[2];
    #pragma unroll
    for (int dyb = 0; dyb < 2; ++dyb) {
      int row = dyb * 16 + lr;
      int phys = (sl * 4 + g) ^ lr;             // row & 15 == lr
      vf[dyb] = __builtin_bit_cast(bf16x8, *reinterpret_cast<const uint4*>(&VL[cur][row * 128 + phys * 8]));
    }

    // --- S^T = K * Q^T (3 hi/lo terms), D: c = sl*32+cb*16+4g+r, t = hf*16+lr ---
    f32x4 s[2];
    s[0] = (f32x4)(0.0f);
    s[1] = (f32x4)(0.0f);
    #pragma unroll
    for (int cb = 0; cb < 2; ++cb)
      #pragma unroll
      for (int f = 0; f < 2; ++f) {
        s[cb] = __builtin_amdgcn_mfma_f32_16x16x32_bf16(kh[cb][f], qh[f], s[cb], 0, 0, 0);
        s[cb] = __builtin_amdgcn_mfma_f32_16x16x32_bf16(kl[cb][f], qh[f], s[cb], 0, 0, 0);
        s[cb] = __builtin_amdgcn_mfma_f32_16x16x32_bf16(kh[cb][f], ql[f], s[cb], 0, 0, 0);
      }

    // --- p = exp2(s + bias), no running max (f32/bf16 exponent range suffices) ---
    const int cbias = st * 128 + sl * 32;
    unsigned pw[2][2];
    #pragma unroll
    for (int cb = 0; cb < 2; ++cb) {
      f32x4 bv = *reinterpret_cast<const f32x4*>(bias + cbias + cb * 16 + 4 * g);
      float p0 = __builtin_amdgcn_exp2f(s[cb][0] + bv[0]);
      float p1 = __builtin_amdgcn_exp2f(s[cb][1] + bv[1]);
      float p2 = __builtin_amdgcn_exp2f(s[cb][2] + bv[2]);
      float p3 = __builtin_amdgcn_exp2f(s[cb][3] + bv[3]);
      pw[cb][0] = cvt_pk_bf16(p0, p1);
      pw[cb][1] = cvt_pk_bf16(p2, p3);
    }

    // --- P relayout through wave-private LDS: write c-pairs, read A-fragments ---
    #pragma unroll
    for (int cb = 0; cb < 2; ++cb) {
      uint2 w2;
      w2.x = pw[cb][0];
      w2.y = pw[cb][1];
      p_lds[wid][lr][cb * 4 + g] = w2;          // words (c/2) = cb*8+2g, +1
    }
    uint2 ra = p_lds[wid][lr][2 * g];           // c = 8g..8g+3
    uint2 rb = p_lds[wid][lr][2 * g + 1];       // c = 8g+4..8g+7
    bf16x8 pa = __builtin_bit_cast(bf16x8, make_uint4(ra.x, ra.y, rb.x, rb.y));

    // --- PV + ones-denominator; D: t_rel = 4g+r, dy = dyb*16+lr ---
    acc[0] = __builtin_amdgcn_mfma_f32_16x16x32_bf16(pa, vf[0], acc[0], 0, 0, 0);
    acc[1] = __builtin_amdgcn_mfma_f32_16x16x32_bf16(pa, vf[1], acc[1], 0, 0, 0);
    den    = __builtin_amdgcn_mfma_f32_16x16x32_bf16(pa, vones, den, 0, 0, 0);

    __syncthreads();   // drains vmcnt (stage done) + all waves done reading cur
  }

  // --- stage per-wave partials, combine 4 slices per target-half ---
  #pragma unroll
  for (int dyb = 0; dyb < 2; ++dyb)
    #pragma unroll
    for (int r = 0; r < 4; ++r)
      acc_lds[wid][4 * g + r][dyb * 16 + lr] = acc[dyb][r];
  if (lr == 0) {
    #pragma unroll
    for (int r = 0; r < 4; ++r) den_lds[wid][4 * g + r] = den[r];
  }
  __syncthreads();

  #pragma unroll
  for (int item = tid; item < 1024; item += 512) {
    int h2 = item >> 9, rem = item & 511;
    int t = rem >> 5, dy = rem & 31;
    float num = 0.f, dn = 0.f;
    #pragma unroll
    for (int w = 0; w < 4; ++w) {
      num += acc_lds[h2 * 4 + w][t][dy];
      dn += den_lds[h2 * 4 + w][t];
    }
    out[(tbase + h2 * 16 + t) * 32 + dy] = num / dn;
  }
}

extern "C" void kernel_launch(void* const* d_in, const int* in_sizes, int n_in,
                              void* d_out, int out_size, void* d_ws, size_t ws_size,
                              hipStream_t stream)
{
  const float* zc = (const float*)d_in[0];   // z_context (8192,64)
  const float* yc = (const float*)d_in[1];   // y_context (8192,32)
  const float* zt = (const float*)d_in[2];   // z_target  (8192,64)
  const float* W  = (const float*)d_in[3];   // W (64,64)

  unsigned short* Qh = (unsigned short*)d_ws;        // 8192*64
  unsigned short* Ql = Qh + 8192 * 64;
  unsigned short* Kh = Ql + 8192 * 64;
  unsigned short* Kl = Kh + 8192 * 64;
  unsigned short* Vt = Kl + 8192 * 64;               // 32*8192
  float* bias = (float*)(Vt + 32 * 8192);            // 8192 f32
  float* Msym = bias + 8192;                         // 4096 f32 (total ~4.8 MB)

  msym_kernel<<<16, 256, 0, stream>>>(W, Msym);
  prep_kernel<<<6176, 256, 0, stream>>>(zc, yc, zt, Msym, Qh, Ql, Kh, Kl, Vt, bias);
  attn_kernel<<<256, 512, 0, stream>>>(Qh, Ql, Kh, Kl, Vt, bias, (float*)d_out);
}

// Round 11
// 75.504 us; speedup vs baseline: 1.5755x; 1.5755x over previous
//
#include <hip/hip_runtime.h>
#include <hip/hip_bf16.h>

// Interpolator == attention: out = softmax_c(z_t^T (W+W^T) z_c - q_cc[c]) @ y_context
// Msym = log2e*(W+W^T) f32; Q = z_target @ Msym (hi/lo bf16); K = z_context (hi/lo bf16)
// bias[c] = -0.5 * z_c^T Msym z_c (f32); V^T bf16 [32][8192]. No online max
// (exp2-domain logits fit f32 exponent range -- proven R8).
//
// R11: bisect+fix. prep = R8 byte-exact (known good). attn = R10 geometry
// (block: 128 targets x 2048-context quarter, 8 waves x 16 targets, x8 K reuse)
// re-expressed in the R8-proven per-cb fused dataflow (no s[8] materialization).

typedef float f32x4 __attribute__((ext_vector_type(4)));
typedef __bf16 bf16x8 __attribute__((ext_vector_type(8)));

#define LOG2E 1.4426950408889634f

static __device__ __forceinline__ unsigned short f2bf(float x) {
  unsigned u = __float_as_uint(x);
  u += 0x7fffu + ((u >> 16) & 1u);   // RNE
  return (unsigned short)(u >> 16);
}
static __device__ __forceinline__ float bf2f(unsigned short h) {
  return __uint_as_float(((unsigned)h) << 16);
}
static __device__ __forceinline__ bf16x8 ldg8(const unsigned short* p) {
  uint4 u = *reinterpret_cast<const uint4*>(p);
  return __builtin_bit_cast(bf16x8, u);
}
static __device__ __forceinline__ unsigned cvt_pk_bf16(float lo, float hi) {
  unsigned r;
  asm("v_cvt_pk_bf16_f32 %0, %1, %2" : "=v"(r) : "v"(lo), "v"(hi));
  return r;
}
// direct global->LDS DMA, 16B/lane; LDS dest = wave-uniform base + lane*16
static __device__ __forceinline__ void gl2lds(const unsigned short* g, unsigned short* l) {
  __builtin_amdgcn_global_load_lds(
      (const __attribute__((address_space(1))) unsigned int*)g,
      (__attribute__((address_space(3))) unsigned int*)l, 16, 0, 0);
}

__global__ void msym_kernel(const float* __restrict__ W, float* __restrict__ Msym) {
  int idx = blockIdx.x * 256 + threadIdx.x;   // 16 blocks -> 4096 elems
  int k = idx >> 6, d = idx & 63;
  Msym[idx] = LOG2E * (W[k * 64 + d] + W[d * 64 + k]);
}

// R8's passing prep, byte-exact: grid 6176
__global__ void prep_kernel(const float* __restrict__ zc, const float* __restrict__ yc,
                            const float* __restrict__ zt, const float* __restrict__ Msym,
                            unsigned short* __restrict__ Qh, unsigned short* __restrict__ Ql,
                            unsigned short* __restrict__ Kh, unsigned short* __restrict__ Kl,
                            unsigned short* __restrict__ Vt, float* __restrict__ bias)
{
  int b = blockIdx.x, tid = threadIdx.x;
  if (b < 2048) {                       // Q = z_t @ Msym, hi/lo split (coalesced Msym)
    int idx = b * 256 + tid;
    int t = idx >> 6, d = idx & 63;
    const float* z = zt + t * 64;
    float q = 0.f;
    #pragma unroll 8
    for (int k = 0; k < 64; ++k) q = fmaf(z[k], Msym[k * 64 + d], q);
    unsigned short h = f2bf(q);
    Qh[idx] = h;
    Ql[idx] = f2bf(q - bf2f(h));
  } else if (b < 4096) {                // K hi/lo split
    int idx = (b - 2048) * 256 + tid;
    float v = zc[idx];
    unsigned short h = f2bf(v);
    Kh[idx] = h;
    Kl[idx] = f2bf(v - bf2f(h));
  } else if (b < 6144) {                // bias[c] = -0.5 * z_c^T Msym z_c, one wave per c
    int c = (b - 4096) * 4 + (tid >> 6), j = tid & 63;
    const float* z = zc + c * 64;
    float cs = 0.f;
    #pragma unroll 8
    for (int i = 0; i < 64; ++i) cs = fmaf(z[i], Msym[i * 64 + j], cs);
    float part = cs * z[j];
    #pragma unroll
    for (int off = 32; off >= 1; off >>= 1) part += __shfl_xor(part, off, 64);
    if (j == 0) bias[c] = -0.5f * part;
  } else {                              // V transpose via LDS (alignment-safe)
    __shared__ float vt[256][33];
    int cbase = (b - 6144) * 256;       // 256 contexts per block
    #pragma unroll
    for (int k = 0; k < 32; ++k) {
      int e = k * 256 + tid;            // e = c_rel*32 + dy, coalesced read
      vt[e >> 5][e & 31] = yc[cbase * 32 + e];
    }
    __syncthreads();
    #pragma unroll
    for (int k = 0; k < 32; ++k)        // k = dy; consecutive tid -> consecutive c
      Vt[k * 8192 + cbase + tid] = f2bf(vt[tid][k]);
  }
}

// ---------------- attention kernel ----------------
// LDS supertile: 128 contexts. KhL/KlL rows = 128B (64 bf16), 8 chunks of 16B,
// physical chunk p holds logical p ^ (row&7). VL rows = 256B (128 bf16), 16
// chunks, physical p holds logical p ^ (row&15). Staging pre-swizzles the
// GLOBAL source so the gl2lds LDS destination stays linear (m173 pattern).

#define STAGE(NB, C0) { \
  const int C0_ = (C0); \
  _Pragma("unroll") \
  for (int i2 = 0; i2 < 2; ++i2) { \
    int i = wid + i2 * 8;                       /* 16 K instr-groups */ \
    int row = i * 8 + (lane >> 3); \
    int lchunk = (lane & 7) ^ (lane >> 3); \
    gl2lds(Kh + (C0_ + row) * 64 + lchunk * 8, &KhL[NB][i * 512]); \
    gl2lds(Kl + (C0_ + row) * 64 + lchunk * 8, &KlL[NB][i * 512]); \
  } \
  { \
    int row = wid * 4 + (lane >> 4);            /* V rows = dy 0..31 */ \
    int lchunk = (lane & 15) ^ (row & 15); \
    gl2lds(Vt + row * 8192 + C0_ + lchunk * 8, &VL[NB][wid * 512]); \
  } }

__global__ __launch_bounds__(512, 1) void attn_kernel(
    const unsigned short* __restrict__ Qh, const unsigned short* __restrict__ Ql,
    const unsigned short* __restrict__ Kh, const unsigned short* __restrict__ Kl,
    const unsigned short* __restrict__ Vt, const float* __restrict__ bias,
    float* __restrict__ outAcc, float* __restrict__ denA)
{
  __shared__ unsigned short KhL[2][128 * 64];   // 2 x 16 KB
  __shared__ unsigned short KlL[2][128 * 64];   // 2 x 16 KB
  __shared__ unsigned short VL[2][32 * 128];    // 2 x 8 KB
  __shared__ __align__(16) uint2 p_lds[8][16][34];  // [wave][t][32 uint2 + 2 pad]

  const int tid = threadIdx.x;
  const int wid = tid >> 6, lane = tid & 63;
  const int lr = lane & 15, g = lane >> 4;
  const int tt = blockIdx.x >> 2, cq = blockIdx.x & 3;
  const int tbase = tt * 128 + wid * 16;        // this wave's 16 targets
  const int cqbase = cq * 2048;                 // this block's context quarter

  // Q fragments (B-operand): lane holds Q[tbase + lr][f*32 + 8g .. +7]
  bf16x8 qh[2], ql[2];
  #pragma unroll
  for (int f = 0; f < 2; ++f) {
    int off = (tbase + lr) * 64 + f * 32 + 8 * g;
    qh[f] = ldg8(Qh + off);
    ql[f] = ldg8(Ql + off);
  }

  uint4 ones_bits = make_uint4(0x3F803F80u, 0x3F803F80u, 0x3F803F80u, 0x3F803F80u);
  bf16x8 vones = __builtin_bit_cast(bf16x8, ones_bits);

  f32x4 acc[2];                                 // [dyb]; D: t_rel=4g+r, dy=dyb*16+lr
  f32x4 den;                                    // denominator (all dy cols equal)
  acc[0] = (f32x4)(0.0f);
  acc[1] = (f32x4)(0.0f);
  den = (f32x4)(0.0f);

  STAGE(0, cqbase)
  __syncthreads();

  for (int st = 0; st < 16; ++st) {
    const int cur = st & 1;
    if (st + 1 < 16) STAGE(cur ^ 1, cqbase + (st + 1) * 128)

    const int cbias = cqbase + st * 128;

    // --- per-cb fused: QK^T -> +bias -> exp2 -> pack -> p_lds write (R8 idiom) ---
    #pragma unroll
    for (int cb = 0; cb < 8; ++cb) {
      int row = cb * 16 + lr;
      int phys0 = g ^ (row & 7);
      int phys1 = (4 + g) ^ (row & 7);
      int off0 = row * 64 + phys0 * 8;
      int off1 = row * 64 + phys1 * 8;
      bf16x8 kh0 = __builtin_bit_cast(bf16x8, *reinterpret_cast<const uint4*>(&KhL[cur][off0]));
      bf16x8 kl0 = __builtin_bit_cast(bf16x8, *reinterpret_cast<const uint4*>(&KlL[cur][off0]));
      bf16x8 kh1 = __builtin_bit_cast(bf16x8, *reinterpret_cast<const uint4*>(&KhL[cur][off1]));
      bf16x8 kl1 = __builtin_bit_cast(bf16x8, *reinterpret_cast<const uint4*>(&KlL[cur][off1]));
      f32x4 sv = (f32x4)(0.0f);
      sv = __builtin_amdgcn_mfma_f32_16x16x32_bf16(kh0, qh[0], sv, 0, 0, 0);
      sv = __builtin_amdgcn_mfma_f32_16x16x32_bf16(kl0, qh[0], sv, 0, 0, 0);
      sv = __builtin_amdgcn_mfma_f32_16x16x32_bf16(kh0, ql[0], sv, 0, 0, 0);
      sv = __builtin_amdgcn_mfma_f32_16x16x32_bf16(kh1, qh[1], sv, 0, 0, 0);
      sv = __builtin_amdgcn_mfma_f32_16x16x32_bf16(kl1, qh[1], sv, 0, 0, 0);
      sv = __builtin_amdgcn_mfma_f32_16x16x32_bf16(kh1, ql[1], sv, 0, 0, 0);
      // D-layout: element r <-> context cb*16 + 4g + r, target = tbase + lr
      f32x4 bv = *reinterpret_cast<const f32x4*>(bias + cbias + cb * 16 + 4 * g);
      float p0 = __builtin_amdgcn_exp2f(sv[0] + bv[0]);
      float p1 = __builtin_amdgcn_exp2f(sv[1] + bv[1]);
      float p2 = __builtin_amdgcn_exp2f(sv[2] + bv[2]);
      float p3 = __builtin_amdgcn_exp2f(sv[3] + bv[3]);
      uint2 w2;
      w2.x = cvt_pk_bf16(p0, p1);
      w2.y = cvt_pk_bf16(p2, p3);
      p_lds[wid][lr][cb * 4 + g] = w2;          // entry e holds contexts 4e..4e+3
    }

    // --- PV + ones-denominator over 4 k-slices of 32 contexts ---
    #pragma unroll
    for (int ks = 0; ks < 4; ++ks) {
      uint2 ra = p_lds[wid][lr][ks * 8 + 2 * g];        // c = ks*32+8g .. +3
      uint2 rb = p_lds[wid][lr][ks * 8 + 2 * g + 1];    // c = ks*32+8g+4 .. +7
      bf16x8 pa = __builtin_bit_cast(bf16x8, make_uint4(ra.x, ra.y, rb.x, rb.y));
      #pragma unroll
      for (int dyb = 0; dyb < 2; ++dyb) {
        int row = dyb * 16 + lr;
        int phys = (ks * 4 + g) ^ lr;           // row & 15 == lr
        bf16x8 vf = __builtin_bit_cast(bf16x8, *reinterpret_cast<const uint4*>(&VL[cur][row * 128 + phys * 8]));
        acc[dyb] = __builtin_amdgcn_mfma_f32_16x16x32_bf16(pa, vf, acc[dyb], 0, 0, 0);
      }
      den = __builtin_amdgcn_mfma_f32_16x16x32_bf16(pa, vones, den, 0, 0, 0);
    }

    __syncthreads();   // drains vmcnt (stage done) + all waves done with cur
  }

  // --- accumulate quarter partials; D: t_rel = 4g+r, dy = dyb*16+lr ---
  #pragma unroll
  for (int dyb = 0; dyb < 2; ++dyb)
    #pragma unroll
    for (int r = 0; r < 4; ++r)
      atomicAdd(&outAcc[(tbase + 4 * g + r) * 32 + dyb * 16 + lr], acc[dyb][r]);
  if (lr == 0) {
    #pragma unroll
    for (int r = 0; r < 4; ++r)
      atomicAdd(&denA[tbase + 4 * g + r], den[r]);
  }
}

// out[t][dy] = num_sum / den_sum
__global__ void divide_kernel(float* __restrict__ out, const float* __restrict__ denA)
{
  int i = blockIdx.x * 256 + threadIdx.x;   // 8192*32
  out[i] = out[i] / denA[i >> 5];
}

extern "C" void kernel_launch(void* const* d_in, const int* in_sizes, int n_in,
                              void* d_out, int out_size, void* d_ws, size_t ws_size,
                              hipStream_t stream)
{
  const float* zc = (const float*)d_in[0];   // z_context (8192,64)
  const float* yc = (const float*)d_in[1];   // y_context (8192,32)
  const float* zt = (const float*)d_in[2];   // z_target  (8192,64)
  const float* W  = (const float*)d_in[3];   // W (64,64)

  unsigned short* Qh = (unsigned short*)d_ws;        // 8192*64 u16
  unsigned short* Ql = Qh + 8192 * 64;
  unsigned short* Kh = Ql + 8192 * 64;
  unsigned short* Kl = Kh + 8192 * 64;
  unsigned short* Vt = Kl + 8192 * 64;               // 32*8192 u16
  float* bias = (float*)(Vt + 32 * 8192);            // 8192 f32
  float* Msym = bias + 8192;                         // 4096 f32
  float* denA = Msym + 4096;                         // 8192 f32 (ws total ~4.83 MB)
  float* out  = (float*)d_out;

  hipMemsetAsync(out, 0, 8192 * 32 * sizeof(float), stream);
  hipMemsetAsync(denA, 0, 8192 * sizeof(float), stream);
  msym_kernel<<<16, 256, 0, stream>>>(W, Msym);
  prep_kernel<<<6176, 256, 0, stream>>>(zc, yc, zt, Msym, Qh, Ql, Kh, Kl, Vt, bias);
  attn_kernel<<<256, 512, 0, stream>>>(Qh, Ql, Kh, Kl, Vt, bias, out, denA);
  divide_kernel<<<1024, 256, 0, stream>>>(out, denA);
}

// Round 16
// 72.558 us; speedup vs baseline: 1.6395x; 1.0406x over previous
//
#include <hip/hip_runtime.h>
#include <hip/hip_bf16.h>

// Interpolator == attention: out = softmax_c(z_t^T (W+W^T) z_c - q_cc[c]) @ y_context
// Msym = log2e*(W+W^T) f32; Q = z_target @ Msym (hi/lo bf16); K = z_context (hi/lo bf16)
// bias[c] = -0.5 * z_c^T Msym z_c (f32); V^T bf16 [32][8192]. No online max.
//
// R16 = R11's PROVEN inner body (16 targets/wave, per-cb fused) with the
// double-buffer traded for occupancy: single 40KB stage, LDS 75776 B,
// __launch_bounds__(512,2) -> 2 blocks/CU; grid 512 = 64 t-tiles x 8
// context-eighths (1024 ctx). Co-resident block hides stage latency (m114).
// R12-R15's 32-target structure abandoned (4 unexplained schedule-dependent
// failures); R11 body lines are copied verbatim.

typedef float f32x4 __attribute__((ext_vector_type(4)));
typedef __bf16 bf16x8 __attribute__((ext_vector_type(8)));

#define LOG2E 1.4426950408889634f

static __device__ __forceinline__ unsigned short f2bf(float x) {
  unsigned u = __float_as_uint(x);
  u += 0x7fffu + ((u >> 16) & 1u);   // RNE
  return (unsigned short)(u >> 16);
}
static __device__ __forceinline__ float bf2f(unsigned short h) {
  return __uint_as_float(((unsigned)h) << 16);
}
static __device__ __forceinline__ bf16x8 ldg8(const unsigned short* p) {
  uint4 u = *reinterpret_cast<const uint4*>(p);
  return __builtin_bit_cast(bf16x8, u);
}
static __device__ __forceinline__ unsigned cvt_pk_bf16(float lo, float hi) {
  unsigned r;
  asm("v_cvt_pk_bf16_f32 %0, %1, %2" : "=v"(r) : "v"(lo), "v"(hi));
  return r;
}
// direct global->LDS DMA, 16B/lane; LDS dest = wave-uniform base + lane*16
static __device__ __forceinline__ void gl2lds(const unsigned short* g, unsigned short* l) {
  __builtin_amdgcn_global_load_lds(
      (const __attribute__((address_space(1))) unsigned int*)g,
      (__attribute__((address_space(3))) unsigned int*)l, 16, 0, 0);
}

__global__ void msym_kernel(const float* __restrict__ W, float* __restrict__ Msym) {
  int idx = blockIdx.x * 256 + threadIdx.x;   // 16 blocks -> 4096 elems
  int k = idx >> 6, d = idx & 63;
  Msym[idx] = LOG2E * (W[k * 64 + d] + W[d * 64 + k]);
}

// R8's passing prep, byte-exact: grid 6176
__global__ void prep_kernel(const float* __restrict__ zc, const float* __restrict__ yc,
                            const float* __restrict__ zt, const float* __restrict__ Msym,
                            unsigned short* __restrict__ Qh, unsigned short* __restrict__ Ql,
                            unsigned short* __restrict__ Kh, unsigned short* __restrict__ Kl,
                            unsigned short* __restrict__ Vt, float* __restrict__ bias)
{
  int b = blockIdx.x, tid = threadIdx.x;
  if (b < 2048) {                       // Q = z_t @ Msym, hi/lo split (coalesced Msym)
    int idx = b * 256 + tid;
    int t = idx >> 6, d = idx & 63;
    const float* z = zt + t * 64;
    float q = 0.f;
    #pragma unroll 8
    for (int k = 0; k < 64; ++k) q = fmaf(z[k], Msym[k * 64 + d], q);
    unsigned short h = f2bf(q);
    Qh[idx] = h;
    Ql[idx] = f2bf(q - bf2f(h));
  } else if (b < 4096) {                // K hi/lo split
    int idx = (b - 2048) * 256 + tid;
    float v = zc[idx];
    unsigned short h = f2bf(v);
    Kh[idx] = h;
    Kl[idx] = f2bf(v - bf2f(h));
  } else if (b < 6144) {                // bias[c] = -0.5 * z_c^T Msym z_c, one wave per c
    int c = (b - 4096) * 4 + (tid >> 6), j = tid & 63;
    const float* z = zc + c * 64;
    float cs = 0.f;
    #pragma unroll 8
    for (int i = 0; i < 64; ++i) cs = fmaf(z[i], Msym[i * 64 + j], cs);
    float part = cs * z[j];
    #pragma unroll
    for (int off = 32; off >= 1; off >>= 1) part += __shfl_xor(part, off, 64);
    if (j == 0) bias[c] = -0.5f * part;
  } else {                              // V transpose via LDS (alignment-safe)
    __shared__ float vt[256][33];
    int cbase = (b - 6144) * 256;       // 256 contexts per block
    #pragma unroll
    for (int k = 0; k < 32; ++k) {
      int e = k * 256 + tid;            // e = c_rel*32 + dy, coalesced read
      vt[e >> 5][e & 31] = yc[cbase * 32 + e];
    }
    __syncthreads();
    #pragma unroll
    for (int k = 0; k < 32; ++k)        // k = dy; consecutive tid -> consecutive c
      Vt[k * 8192 + cbase + tid] = f2bf(vt[tid][k]);
  }
}

// ---------------- attention kernel ----------------
// LDS supertile: 128 contexts, SINGLE-buffered. KhL/KlL rows = 128B (64 bf16),
// 8 chunks of 16B, physical chunk p holds logical p ^ (row&7). VL rows = 256B
// (128 bf16), 16 chunks, physical p holds logical p ^ (row&15). Staging
// pre-swizzles the GLOBAL source so the gl2lds LDS dest stays linear (m173).

#define STAGE(C0) { \
  const int C0_ = (C0); \
  _Pragma("unroll") \
  for (int i2 = 0; i2 < 2; ++i2) { \
    int i = wid + i2 * 8;                       /* 16 K instr-groups */ \
    int row = i * 8 + (lane >> 3); \
    int lchunk = (lane & 7) ^ (lane >> 3); \
    gl2lds(Kh + (C0_ + row) * 64 + lchunk * 8, &KhL[i * 512]); \
    gl2lds(Kl + (C0_ + row) * 64 + lchunk * 8, &KlL[i * 512]); \
  } \
  { \
    int row = wid * 4 + (lane >> 4);            /* V rows = dy 0..31 */ \
    int lchunk = (lane & 15) ^ (row & 15); \
    gl2lds(Vt + row * 8192 + C0_ + lchunk * 8, &VL[wid * 512]); \
  } }

__global__ __launch_bounds__(512, 2) void attn_kernel(
    const unsigned short* __restrict__ Qh, const unsigned short* __restrict__ Ql,
    const unsigned short* __restrict__ Kh, const unsigned short* __restrict__ Kl,
    const unsigned short* __restrict__ Vt, const float* __restrict__ bias,
    float* __restrict__ outAcc, float* __restrict__ denA)
{
  __shared__ unsigned short KhL[128 * 64];      // 16 KB
  __shared__ unsigned short KlL[128 * 64];      // 16 KB
  __shared__ unsigned short VL[32 * 128];       // 8 KB
  __shared__ __align__(16) uint2 p_lds[8][16][34];  // 34 KB; total 75776 B

  const int tid = threadIdx.x;
  const int wid = tid >> 6, lane = tid & 63;
  const int lr = lane & 15, g = lane >> 4;
  const int tt = blockIdx.x >> 3, cq = blockIdx.x & 7;
  const int tbase = tt * 128 + wid * 16;        // this wave's 16 targets
  const int cqbase = cq * 1024;                 // this block's context eighth

  // Q fragments (B-operand): lane holds Q[tbase + lr][f*32 + 8g .. +7]
  bf16x8 qh[2], ql[2];
  #pragma unroll
  for (int f = 0; f < 2; ++f) {
    int off = (tbase + lr) * 64 + f * 32 + 8 * g;
    qh[f] = ldg8(Qh + off);
    ql[f] = ldg8(Ql + off);
  }

  uint4 ones_bits = make_uint4(0x3F803F80u, 0x3F803F80u, 0x3F803F80u, 0x3F803F80u);
  bf16x8 vones = __builtin_bit_cast(bf16x8, ones_bits);

  f32x4 acc[2];                                 // [dyb]; D: t_rel=4g+r, dy=dyb*16+lr
  f32x4 den;                                    // denominator (all dy cols equal)
  acc[0] = (f32x4)(0.0f);
  acc[1] = (f32x4)(0.0f);
  den = (f32x4)(0.0f);

  for (int st = 0; st < 8; ++st) {
    STAGE(cqbase + st * 128)
    __syncthreads();                            // stage complete (vmcnt drained)

    const int cbias = cqbase + st * 128;

    // --- per-cb fused: QK^T -> +bias -> exp2 -> pack -> p_lds write (R11 body) ---
    #pragma unroll
    for (int cb = 0; cb < 8; ++cb) {
      int row = cb * 16 + lr;
      int phys0 = g ^ (row & 7);
      int phys1 = (4 + g) ^ (row & 7);
      int off0 = row * 64 + phys0 * 8;
      int off1 = row * 64 + phys1 * 8;
      bf16x8 kh0 = __builtin_bit_cast(bf16x8, *reinterpret_cast<const uint4*>(&KhL[off0]));
      bf16x8 kl0 = __builtin_bit_cast(bf16x8, *reinterpret_cast<const uint4*>(&KlL[off0]));
      bf16x8 kh1 = __builtin_bit_cast(bf16x8, *reinterpret_cast<const uint4*>(&KhL[off1]));
      bf16x8 kl1 = __builtin_bit_cast(bf16x8, *reinterpret_cast<const uint4*>(&KlL[off1]));
      f32x4 sv = (f32x4)(0.0f);
      sv = __builtin_amdgcn_mfma_f32_16x16x32_bf16(kh0, qh[0], sv, 0, 0, 0);
      sv = __builtin_amdgcn_mfma_f32_16x16x32_bf16(kl0, qh[0], sv, 0, 0, 0);
      sv = __builtin_amdgcn_mfma_f32_16x16x32_bf16(kh0, ql[0], sv, 0, 0, 0);
      sv = __builtin_amdgcn_mfma_f32_16x16x32_bf16(kh1, qh[1], sv, 0, 0, 0);
      sv = __builtin_amdgcn_mfma_f32_16x16x32_bf16(kl1, qh[1], sv, 0, 0, 0);
      sv = __builtin_amdgcn_mfma_f32_16x16x32_bf16(kh1, ql[1], sv, 0, 0, 0);
      // D-layout: element r <-> context cb*16 + 4g + r, target = tbase + lr
      f32x4 bv = *reinterpret_cast<const f32x4*>(bias + cbias + cb * 16 + 4 * g);
      float p0 = __builtin_amdgcn_exp2f(sv[0] + bv[0]);
      float p1 = __builtin_amdgcn_exp2f(sv[1] + bv[1]);
      float p2 = __builtin_amdgcn_exp2f(sv[2] + bv[2]);
      float p3 = __builtin_amdgcn_exp2f(sv[3] + bv[3]);
      uint2 w2;
      w2.x = cvt_pk_bf16(p0, p1);
      w2.y = cvt_pk_bf16(p2, p3);
      p_lds[wid][lr][cb * 4 + g] = w2;          // entry e holds contexts 4e..4e+3
    }

    // --- PV + ones-denominator over 4 k-slices of 32 contexts (R11 body) ---
    #pragma unroll
    for (int ks = 0; ks < 4; ++ks) {
      uint2 ra = p_lds[wid][lr][ks * 8 + 2 * g];        // c = ks*32+8g .. +3
      uint2 rb = p_lds[wid][lr][ks * 8 + 2 * g + 1];    // c = ks*32+8g+4 .. +7
      bf16x8 pa = __builtin_bit_cast(bf16x8, make_uint4(ra.x, ra.y, rb.x, rb.y));
      #pragma unroll
      for (int dyb = 0; dyb < 2; ++dyb) {
        int row = dyb * 16 + lr;
        int phys = (ks * 4 + g) ^ lr;           // row & 15 == lr
        bf16x8 vf = __builtin_bit_cast(bf16x8, *reinterpret_cast<const uint4*>(&VL[row * 128 + phys * 8]));
        acc[dyb] = __builtin_amdgcn_mfma_f32_16x16x32_bf16(pa, vf, acc[dyb], 0, 0, 0);
      }
      den = __builtin_amdgcn_mfma_f32_16x16x32_bf16(pa, vones, den, 0, 0, 0);
    }

    __syncthreads();   // all waves done reading before next stage overwrites
  }

  // --- accumulate eighth partials; D: t_rel = 4g+r, dy = dyb*16+lr (R11 body) ---
  #pragma unroll
  for (int dyb = 0; dyb < 2; ++dyb)
    #pragma unroll
    for (int r = 0; r < 4; ++r)
      atomicAdd(&outAcc[(tbase + 4 * g + r) * 32 + dyb * 16 + lr], acc[dyb][r]);
  if (lr == 0) {
    #pragma unroll
    for (int r = 0; r < 4; ++r)
      atomicAdd(&denA[tbase + 4 * g + r], den[r]);
  }
}

// out[t][dy] = num_sum / den_sum
__global__ void divide_kernel(float* __restrict__ out, const float* __restrict__ denA)
{
  int i = blockIdx.x * 256 + threadIdx.x;   // 8192*32
  out[i] = out[i] / denA[i >> 5];
}

extern "C" void kernel_launch(void* const* d_in, const int* in_sizes, int n_in,
                              void* d_out, int out_size, void* d_ws, size_t ws_size,
                              hipStream_t stream)
{
  const float* zc = (const float*)d_in[0];   // z_context (8192,64)
  const float* yc = (const float*)d_in[1];   // y_context (8192,32)
  const float* zt = (const float*)d_in[2];   // z_target  (8192,64)
  const float* W  = (const float*)d_in[3];   // W (64,64)

  unsigned short* Qh = (unsigned short*)d_ws;        // 8192*64 u16
  unsigned short* Ql = Qh + 8192 * 64;
  unsigned short* Kh = Ql + 8192 * 64;
  unsigned short* Kl = Kh + 8192 * 64;
  unsigned short* Vt = Kl + 8192 * 64;               // 32*8192 u16
  float* bias = (float*)(Vt + 32 * 8192);            // 8192 f32
  float* Msym = bias + 8192;                         // 4096 f32
  float* denA = Msym + 4096;                         // 8192 f32 (ws total ~4.83 MB)
  float* out  = (float*)d_out;

  hipMemsetAsync(out, 0, 8192 * 32 * sizeof(float), stream);
  hipMemsetAsync(denA, 0, 8192 * sizeof(float), stream);
  msym_kernel<<<16, 256, 0, stream>>>(W, Msym);
  prep_kernel<<<6176, 256, 0, stream>>>(zc, yc, zt, Msym, Qh, Ql, Kh, Kl, Vt, bias);
  attn_kernel<<<512, 512, 0, stream>>>(Qh, Ql, Kh, Kl, Vt, bias, out, denA);
  divide_kernel<<<1024, 256, 0, stream>>>(out, denA);
}